// Round 1
// baseline (170.744 us; speedup 1.0000x reference)
//
#include <hip/hip_runtime.h>

// AttentionNet: N=128 batch, a1=a2=64, f=2.
// One block per n, 1024 threads = 16 waves, 4 rows per wave per attention stage.
// Inner loop is register-resident: lane j owns row j (prescaled), row-i operand
// broadcast via v_readlane -> zero LDS traffic in the hot loop.

constexpr int A    = 64;
constexpr int PAD  = 65;   // LDS row stride: 65 = 2-way bank aliasing (free)
constexpr int NW   = 16;   // waves per block
constexpr int RPW  = 4;    // rows per wave (64 / 16)
constexpr float L2E  = 1.4426950408889634f;
constexpr float EPSF = 1e-6f;

__device__ __forceinline__ float bcast_lane(float v, int srcLane) {
    return __int_as_float(__builtin_amdgcn_readlane(__float_as_int(v), srcLane));
}

// Compute pre-softmax m values for this wave's RPW rows; store into mbuf[0..63].
// load(k) returns this lane's row value at position k (lane <-> row j).
template <typename LoadF>
__device__ __forceinline__ void att_rows(LoadF load, float W0, float W1, float bb,
                                         int wv, int lane, float* mbuf)
{
    float acc[RPW];
#pragma unroll
    for (int ii = 0; ii < RPW; ++ii) acc[ii] = 0.0f;

#pragma unroll 1
    for (int c = 0; c < A / 16; ++c) {
        float ar[16], br[16];
#pragma unroll
        for (int kk = 0; kk < 16; ++kk) {
            float v = load(c * 16 + kk);
            // sigmoid(t) = 1/(1+2^(-t*log2e)); fold scales so inner op is add+exp2.
            ar[kk] = -L2E * (W0 * v + bb);   // lane's own (j) contribution + bias
            br[kk] = -L2E * (W1 * v);        // broadcast-source (i) contribution
        }
#pragma unroll
        for (int kk = 0; kk < 16; ++kk) {
#pragma unroll
            for (int ii = 0; ii < RPW; ++ii) {
                const int i = wv * RPW + ii;
                float z = ar[kk] + bcast_lane(br[kk], i);
                float e = exp2f(z);                       // v_exp_f32
                acc[ii] += __builtin_amdgcn_rcpf(1.0f + e); // v_rcp_f32, ~1 ulp
            }
        }
    }

    // acc[ii] = 64 * c[i][j] with j = lane. Row stats across lanes.
#pragma unroll
    for (int ii = 0; ii < RPW; ++ii) {
        float cv = acc[ii] * (1.0f / 64.0f);
        float s = cv, mx = cv;
        for (int off = 1; off < 64; off <<= 1) {
            s += __shfl_xor(s, off, 64);
            mx = fmaxf(mx, __shfl_xor(mx, off, 64));
        }
        // mean_j (c/(max+eps)) = (mean_j c)/(max+eps)
        float mp = (s * (1.0f / 64.0f)) / (mx + EPSF);
        if (lane == 0) mbuf[wv * RPW + ii] = mp;
    }
}

// relu(m*sharp+th) -> softmax -> (optional) maxnorm. Wave 0 does the work.
__device__ __forceinline__ void softmax_vec(const float* mbuf, float* vbuf,
                                            float sharp, float th, bool last,
                                            int wv, int lane, float* gout)
{
    __syncthreads();   // all m values written
    if (wv == 0) {
        float v = fmaxf(0.0f, mbuf[lane] * sharp + th);
        float mx = v;
        for (int off = 1; off < 64; off <<= 1) mx = fmaxf(mx, __shfl_xor(mx, off, 64));
        float e = __expf(v - mx);
        float s = e;
        for (int off = 1; off < 64; off <<= 1) s += __shfl_xor(s, off, 64);
        float r = e / s;
        if (!last) {
            float rm = r;
            for (int off = 1; off < 64; off <<= 1) rm = fmaxf(rm, __shfl_xor(rm, off, 64));
            r = r / (rm + EPSF);
            vbuf[lane] = r;
        } else {
            gout[lane] = r;
        }
    }
    __syncthreads();   // vec visible to all waves
}

__global__ __launch_bounds__(1024, 1)
void attn_net_kernel(const float* __restrict__ x,
                     const float* __restrict__ fcW, const float* __restrict__ fcb,
                     const float* __restrict__ p1W, const float* __restrict__ p1b,
                     const float* __restrict__ p1s, const float* __restrict__ p1t,
                     const float* __restrict__ p2W, const float* __restrict__ p2b,
                     const float* __restrict__ p2s, const float* __restrict__ p2t,
                     const float* __restrict__ oW,  const float* __restrict__ ob,
                     const float* __restrict__ os,  const float* __restrict__ ot,
                     float* __restrict__ out)
{
    __shared__ float h0[A * PAD];
    __shared__ float h1[A * PAD];
    __shared__ float mbuf[A];
    __shared__ float v1buf[A];
    __shared__ float v2buf[A];

    const int tid  = threadIdx.x;
    const int lane = tid & 63;
    const int wv   = tid >> 6;
    const int n    = blockIdx.x;

    // ---- Phase A: h0/h1 = relu(fc(x)) into LDS (padded) ----
    {
        const float4* x0v = (const float4*)(x + (size_t)n * 2 * A * A);
        const float4* x1v = x0v + (A * A / 4);
        float4 a = x0v[tid];
        float4 c = x1v[tid];
        const float w00 = fcW[0], w01 = fcW[1], w10 = fcW[2], w11 = fcW[3];
        const float bb0 = fcb[0], bb1 = fcb[1];
        const int e = tid * 4;
        const int i = e >> 6, j = e & 63;   // j..j+3 stay in one row
        float* q0 = &h0[i * PAD + j];
        float* q1 = &h1[i * PAD + j];
        q0[0] = fmaxf(0.f, w00 * a.x + w01 * c.x + bb0);
        q0[1] = fmaxf(0.f, w00 * a.y + w01 * c.y + bb0);
        q0[2] = fmaxf(0.f, w00 * a.z + w01 * c.z + bb0);
        q0[3] = fmaxf(0.f, w00 * a.w + w01 * c.w + bb0);
        q1[0] = fmaxf(0.f, w10 * a.x + w11 * c.x + bb1);
        q1[1] = fmaxf(0.f, w10 * a.y + w11 * c.y + bb1);
        q1[2] = fmaxf(0.f, w10 * a.z + w11 * c.z + bb1);
        q1[3] = fmaxf(0.f, w10 * a.w + w11 * c.w + bb1);
    }
    __syncthreads();

    // ---- Phase B: vec1 = att(h0), rows over a1, k over a2 ----
    att_rows([&](int k) { return h0[lane * PAD + k]; },
             p1W[0], p1W[1], p1b[0], wv, lane, mbuf);
    softmax_vec(mbuf, v1buf, p1s[0], p1t[0], /*last=*/false, wv, lane, nullptr);

    // ---- Phase C: vec2 = att(h1^T * vec1), rows over a2, k over a1 ----
    att_rows([&](int k) { return h1[k * PAD + lane] * v1buf[k]; },
             p2W[0], p2W[1], p2b[0], wv, lane, mbuf);
    softmax_vec(mbuf, v2buf, p2s[0], p2t[0], /*last=*/false, wv, lane, nullptr);

    // ---- Phase D: out = att(h0 * vec1[i] * vec2[j]), is_last ----
    const float v1l = v1buf[lane];
    att_rows([&](int k) { return h0[lane * PAD + k] * v1l * v2buf[k]; },
             oW[0], oW[1], ob[0], wv, lane, mbuf);
    softmax_vec(mbuf, nullptr, os[0], ot[0], /*last=*/true, wv, lane,
                out + (size_t)n * A);
}

extern "C" void kernel_launch(void* const* d_in, const int* in_sizes, int n_in,
                              void* d_out, int out_size, void* d_ws, size_t ws_size,
                              hipStream_t stream)
{
    (void)n_in; (void)out_size; (void)d_ws; (void)ws_size;
    const float* x   = (const float*)d_in[0];
    const float* fcW = (const float*)d_in[1];
    const float* fcb = (const float*)d_in[2];
    const float* p1W = (const float*)d_in[3];
    const float* p1b = (const float*)d_in[4];
    const float* p1s = (const float*)d_in[5];
    const float* p1t = (const float*)d_in[6];
    const float* p2W = (const float*)d_in[7];
    const float* p2b = (const float*)d_in[8];
    const float* p2s = (const float*)d_in[9];
    const float* p2t = (const float*)d_in[10];
    const float* oW  = (const float*)d_in[11];
    const float* ob  = (const float*)d_in[12];
    const float* os  = (const float*)d_in[13];
    const float* ot  = (const float*)d_in[14];
    float* out = (float*)d_out;

    const int N = in_sizes[0] / (2 * A * A);   // 128
    attn_net_kernel<<<N, 1024, 0, stream>>>(x, fcW, fcb,
                                            p1W, p1b, p1s, p1t,
                                            p2W, p2b, p2s, p2t,
                                            oW, ob, os, ot, out);
}

// Round 2
// 124.139 us; speedup vs baseline: 1.3754x; 1.3754x over previous
//
#include <hip/hip_runtime.h>

// AttentionNet N=128, a1=a2=64, f=2 — split into 4 kernels for full-chip use:
//   K1: h0 -> stage-B m-values (2 blocks per n, 32 rows each)   grid 256
//   K2: softmax(vec1) + h1*vec1 -> stage-C m-values             grid 256
//   K3: softmax(vec1,vec2) + h0*v1*v2 -> stage-D m-values       grid 256
//   K4: final softmax -> out                                    grid 128
// Inner loop: z-add + v_exp_f32 + add + v_rcp_f32 + acc-add, operands
// register-resident, row-i broadcast via v_readlane (no LDS in hot loop).

constexpr int A   = 64;
constexpr int PAD = 65;   // LDS row stride: (lane+k)%32 banks -> 2-way = free
constexpr float L2E  = 1.4426950408889634f;
constexpr float EPSF = 1e-6f;

__device__ __forceinline__ float bcast(float v, int srcLane) {
    return __int_as_float(__builtin_amdgcn_readlane(__float_as_int(v), srcLane));
}

// m-values for rows row0, row0+1 (lane <-> column j). gm[row] = mean_j/ (max_j + eps).
template <typename LoadF>
__device__ __forceinline__ void att2(LoadF load, float W0, float W1, float bb,
                                     int row0, int lane, float* __restrict__ gm)
{
    float acc0 = 0.f, acc1 = 0.f;
#pragma unroll 1
    for (int c = 0; c < A / 16; ++c) {
        float ar[16], br[16];
#pragma unroll
        for (int kk = 0; kk < 16; ++kk) {
            float v = load(c * 16 + kk);
            // sigmoid(t) = 1/(1 + 2^(-t*log2e)); scales folded into ar/br.
            ar[kk] = -L2E * (W0 * v + bb);
            br[kk] = -L2E * (W1 * v);
        }
#pragma unroll
        for (int kk = 0; kk < 16; ++kk) {
            float z0 = ar[kk] + bcast(br[kk], row0);
            float z1 = ar[kk] + bcast(br[kk], row0 + 1);
            acc0 += __builtin_amdgcn_rcpf(1.0f + __builtin_amdgcn_exp2f(z0));
            acc1 += __builtin_amdgcn_rcpf(1.0f + __builtin_amdgcn_exp2f(z1));
        }
    }
    float s0 = acc0, m0 = acc0, s1 = acc1, m1 = acc1;
#pragma unroll
    for (int off = 1; off < 64; off <<= 1) {
        s0 += __shfl_xor(s0, off, 64);
        m0 = fmaxf(m0, __shfl_xor(m0, off, 64));
        s1 += __shfl_xor(s1, off, 64);
        m1 = fmaxf(m1, __shfl_xor(m1, off, 64));
    }
    if (lane == 0) {
        // acc = 64*c; mean_j c = s/4096, max_j c = m/64.
        gm[row0]     = (s0 * (1.0f / 4096.0f)) / (m0 * (1.0f / 64.0f) + EPSF);
        gm[row0 + 1] = (s1 * (1.0f / 4096.0f)) / (m1 * (1.0f / 64.0f) + EPSF);
    }
}

__device__ __forceinline__ float softmax64(float m, float sharp, float th, bool last)
{
    float v = fmaxf(0.f, m * sharp + th);
    float mx = v;
#pragma unroll
    for (int off = 1; off < 64; off <<= 1) mx = fmaxf(mx, __shfl_xor(mx, off, 64));
    float e = __expf(v - mx);
    float s = e;
#pragma unroll
    for (int off = 1; off < 64; off <<= 1) s += __shfl_xor(s, off, 64);
    float r = e / s;
    if (!last) {
        float rm = r;
#pragma unroll
        for (int off = 1; off < 64; off <<= 1) rm = fmaxf(rm, __shfl_xor(rm, off, 64));
        r = r / (rm + EPSF);
    }
    return r;
}

// ---- K1: stage B ----
__global__ __launch_bounds__(1024, 1)
void k_stageB(const float* __restrict__ x,
              const float* __restrict__ fcW, const float* __restrict__ fcb,
              const float* __restrict__ p1W, const float* __restrict__ p1b,
              float* __restrict__ m1)
{
    __shared__ float h0[A * PAD];
    const int tid = threadIdx.x, lane = tid & 63, wv = tid >> 6;
    const int n = blockIdx.x >> 1, half = blockIdx.x & 1;

    const float4* x0v = (const float4*)(x + (size_t)n * 2 * A * A);
    const float4* x1v = x0v + (A * A / 4);
    float4 a = x0v[tid];
    float4 c = x1v[tid];
    const float w00 = fcW[0], w01 = fcW[1], b0 = fcb[0];
    const int e = tid * 4, i = e >> 6, j = e & 63;
    float* q0 = &h0[i * PAD + j];
    q0[0] = fmaxf(0.f, w00 * a.x + w01 * c.x + b0);
    q0[1] = fmaxf(0.f, w00 * a.y + w01 * c.y + b0);
    q0[2] = fmaxf(0.f, w00 * a.z + w01 * c.z + b0);
    q0[3] = fmaxf(0.f, w00 * a.w + w01 * c.w + b0);
    __syncthreads();

    const int row0 = half * 32 + wv * 2;
    att2([&](int k) { return h0[lane * PAD + k]; },
         p1W[0], p1W[1], p1b[0], row0, lane, m1 + (size_t)n * A);
}

// ---- K2: stage C (rows over a2, k over a1; h1 pre-scaled by vec1[row]) ----
__global__ __launch_bounds__(1024, 1)
void k_stageC(const float* __restrict__ x,
              const float* __restrict__ fcW, const float* __restrict__ fcb,
              const float* __restrict__ p1s, const float* __restrict__ p1t,
              const float* __restrict__ p2W, const float* __restrict__ p2b,
              const float* __restrict__ m1, float* __restrict__ m2)
{
    __shared__ float h1[A * PAD];
    __shared__ float v1buf[A];
    const int tid = threadIdx.x, lane = tid & 63, wv = tid >> 6;
    const int n = blockIdx.x >> 1, half = blockIdx.x & 1;

    const float4* x0v = (const float4*)(x + (size_t)n * 2 * A * A);
    const float4* x1v = x0v + (A * A / 4);
    float4 a = x0v[tid];
    float4 c = x1v[tid];

    if (tid < 64) v1buf[tid] = softmax64(m1[(size_t)n * A + tid], p1s[0], p1t[0], false);
    __syncthreads();

    const float w10 = fcW[2], w11 = fcW[3], b1 = fcb[1];
    const int e = tid * 4, i = e >> 6, j = e & 63;
    const float sc = v1buf[i];            // vec1 is over a1 = h's row index
    float* q1 = &h1[i * PAD + j];
    q1[0] = fmaxf(0.f, w10 * a.x + w11 * c.x + b1) * sc;
    q1[1] = fmaxf(0.f, w10 * a.y + w11 * c.y + b1) * sc;
    q1[2] = fmaxf(0.f, w10 * a.z + w11 * c.z + b1) * sc;
    q1[3] = fmaxf(0.f, w10 * a.w + w11 * c.w + b1) * sc;
    __syncthreads();

    const int row0 = half * 32 + wv * 2;
    att2([&](int k) { return h1[k * PAD + lane]; },   // transposed access
         p2W[0], p2W[1], p2b[0], row0, lane, m2 + (size_t)n * A);
}

// ---- K3: stage D (h0 pre-scaled by vec1[i]*vec2[j]) ----
__global__ __launch_bounds__(1024, 1)
void k_stageD(const float* __restrict__ x,
              const float* __restrict__ fcW, const float* __restrict__ fcb,
              const float* __restrict__ p1s, const float* __restrict__ p1t,
              const float* __restrict__ p2s, const float* __restrict__ p2t,
              const float* __restrict__ oW,  const float* __restrict__ ob,
              const float* __restrict__ m1,  const float* __restrict__ m2,
              float* __restrict__ m3)
{
    __shared__ float h0[A * PAD];
    __shared__ float v1buf[A], v2buf[A];
    const int tid = threadIdx.x, lane = tid & 63, wv = tid >> 6;
    const int n = blockIdx.x >> 1, half = blockIdx.x & 1;

    const float4* x0v = (const float4*)(x + (size_t)n * 2 * A * A);
    const float4* x1v = x0v + (A * A / 4);
    float4 a = x0v[tid];
    float4 c = x1v[tid];

    if (tid < 64)       v1buf[tid]      = softmax64(m1[(size_t)n * A + tid],      p1s[0], p1t[0], false);
    else if (tid < 128) v2buf[tid - 64] = softmax64(m2[(size_t)n * A + tid - 64], p2s[0], p2t[0], false);
    __syncthreads();

    const float w00 = fcW[0], w01 = fcW[1], b0 = fcb[0];
    const int e = tid * 4, i = e >> 6, j = e & 63;
    const float sc = v1buf[i];
    float* q0 = &h0[i * PAD + j];
    q0[0] = fmaxf(0.f, w00 * a.x + w01 * c.x + b0) * sc * v2buf[j];
    q0[1] = fmaxf(0.f, w00 * a.y + w01 * c.y + b0) * sc * v2buf[j + 1];
    q0[2] = fmaxf(0.f, w00 * a.z + w01 * c.z + b0) * sc * v2buf[j + 2];
    q0[3] = fmaxf(0.f, w00 * a.w + w01 * c.w + b0) * sc * v2buf[j + 3];
    __syncthreads();

    const int row0 = half * 32 + wv * 2;
    att2([&](int k) { return h0[lane * PAD + k]; },
         oW[0], oW[1], ob[0], row0, lane, m3 + (size_t)n * A);
}

// ---- K4: final softmax -> out ----
__global__ __launch_bounds__(64, 1)
void k_final(const float* __restrict__ m3,
             const float* __restrict__ os, const float* __restrict__ ot,
             float* __restrict__ out)
{
    const int n = blockIdx.x, lane = threadIdx.x;
    out[(size_t)n * A + lane] = softmax64(m3[(size_t)n * A + lane], os[0], ot[0], true);
}

extern "C" void kernel_launch(void* const* d_in, const int* in_sizes, int n_in,
                              void* d_out, int out_size, void* d_ws, size_t ws_size,
                              hipStream_t stream)
{
    (void)n_in; (void)out_size; (void)ws_size;
    const float* x   = (const float*)d_in[0];
    const float* fcW = (const float*)d_in[1];
    const float* fcb = (const float*)d_in[2];
    const float* p1W = (const float*)d_in[3];
    const float* p1b = (const float*)d_in[4];
    const float* p1s = (const float*)d_in[5];
    const float* p1t = (const float*)d_in[6];
    const float* p2W = (const float*)d_in[7];
    const float* p2b = (const float*)d_in[8];
    const float* p2s = (const float*)d_in[9];
    const float* p2t = (const float*)d_in[10];
    const float* oW  = (const float*)d_in[11];
    const float* ob  = (const float*)d_in[12];
    const float* os  = (const float*)d_in[13];
    const float* ot  = (const float*)d_in[14];
    float* out = (float*)d_out;

    const int N = in_sizes[0] / (2 * A * A);   // 128
    float* ws = (float*)d_ws;
    float* m1 = ws;
    float* m2 = ws + (size_t)N * A;
    float* m3 = ws + (size_t)2 * N * A;

    k_stageB<<<2 * N, 1024, 0, stream>>>(x, fcW, fcb, p1W, p1b, m1);
    k_stageC<<<2 * N, 1024, 0, stream>>>(x, fcW, fcb, p1s, p1t, p2W, p2b, m1, m2);
    k_stageD<<<2 * N, 1024, 0, stream>>>(x, fcW, fcb, p1s, p1t, p2s, p2t, oW, ob, m1, m2, m3);
    k_final<<<N, 64, 0, stream>>>(m3, os, ot, out);
}